// Round 1
// baseline (1963.942 us; speedup 1.0000x reference)
//
#include <hip/hip_runtime.h>

#define N_NODES 100000
#define IN_FEAT 128
#define OUT_FEAT 128
#define NUM_RELS 64
#define EDGES_PER_REL 16384
#define NUM_BASES 16
#define E_TOTAL (NUM_RELS * EDGES_PER_REL)

// ---------------------------------------------------------------------------
// Kernel 1: W[r] = sum_b w_comp[r][b] * weight[b]   -> d_ws (64*128*128 f32)
// ---------------------------------------------------------------------------
__global__ __launch_bounds__(256) void compose_w_kernel(
    const float* __restrict__ weight, const float* __restrict__ w_comp,
    float* __restrict__ W) {
  int idx = blockIdx.x * 256 + threadIdx.x;   // 64*16384 total
  int r  = idx >> 14;                          // block covers a single r
  int io = idx & 16383;
  const float* wc = w_comp + r * NUM_BASES;
  float acc = 0.f;
#pragma unroll
  for (int b = 0; b < NUM_BASES; ++b)
    acc += wc[b] * weight[b * (IN_FEAT * OUT_FEAT) + io];
  W[idx] = acc;
}

// ---------------------------------------------------------------------------
// Kernel 2: out[n] = h_bias + feat[n] @ loop_weight   (64 nodes / block)
// ---------------------------------------------------------------------------
__global__ __launch_bounds__(256) void init_out_kernel(
    const float* __restrict__ feat, const float* __restrict__ loop_w,
    const float* __restrict__ bias, float* __restrict__ out) {
  __shared__ float4 A4[64][32];   // 64 rows x 128 floats, row-major
  int t = threadIdx.x;
  long base = (long)blockIdx.x * 64;
#pragma unroll
  for (int j = 0; j < 8; ++j) {
    int idx = t + j * 256;        // 2048 float4s
    int e = idx >> 5, k4 = idx & 31;
    long n = base + e;
    float4 v = make_float4(0.f, 0.f, 0.f, 0.f);
    if (n < N_NODES) v = ((const float4*)feat)[n * 32 + k4];
    A4[e][k4] = v;
  }
  __syncthreads();
  int og = t & 31, eg = t >> 5;   // 32 out-groups x 8 edge-groups
  float acc[8][4];
#pragma unroll
  for (int j = 0; j < 8; ++j)
#pragma unroll
    for (int d = 0; d < 4; ++d) acc[j][d] = 0.f;

  const float4* W4 = (const float4*)loop_w;   // [128 k][32 og]
  for (int k4 = 0; k4 < 32; ++k4) {
    float4 a[8];
#pragma unroll
    for (int j = 0; j < 8; ++j) a[j] = A4[eg * 8 + j][k4];
#pragma unroll
    for (int d = 0; d < 4; ++d) {
      float4 w = W4[(k4 * 4 + d) * 32 + og];
#pragma unroll
      for (int j = 0; j < 8; ++j) {
        float av = ((const float*)&a[j])[d];
        acc[j][0] += av * w.x;
        acc[j][1] += av * w.y;
        acc[j][2] += av * w.z;
        acc[j][3] += av * w.w;
      }
    }
  }
  float4 b = ((const float4*)bias)[og];
#pragma unroll
  for (int j = 0; j < 8; ++j) {
    long n = base + eg * 8 + j;
    if (n < N_NODES) {
      float4 v = make_float4(acc[j][0] + b.x, acc[j][1] + b.y,
                             acc[j][2] + b.z, acc[j][3] + b.w);
      ((float4*)out)[n * 32 + og] = v;
    }
  }
}

// ---------------------------------------------------------------------------
// Kernel 3: per-edge msg = (feat[src] @ W[rel]) * norm; atomicAdd to out[dst]
// 64 edges per block; edges sorted by relation, 256 blocks per relation.
// ---------------------------------------------------------------------------
__global__ __launch_bounds__(256) void edge_msg_kernel(
    const float* __restrict__ feat, const float* __restrict__ W,
    const float* __restrict__ norm, const int* __restrict__ src,
    const int* __restrict__ dst, float* __restrict__ out) {
  __shared__ float4 A4[64][32];
  __shared__ int   s_src[64];
  __shared__ int   s_dst[64];
  __shared__ float s_norm[64];
  int t = threadIdx.x;
  long base = (long)blockIdx.x * 64;
  int rel = blockIdx.x >> 8;                 // 16384/64 = 256 blocks per rel
  const float4* Wr4 = (const float4*)(W + (long)rel * IN_FEAT * OUT_FEAT);

  if (t < 64) {
    s_src[t]  = src[base + t];
    s_dst[t]  = dst[base + t];
    s_norm[t] = norm[base + t];
  }
  __syncthreads();
#pragma unroll
  for (int j = 0; j < 8; ++j) {
    int idx = t + j * 256;
    int e = idx >> 5, k4 = idx & 31;
    A4[e][k4] = ((const float4*)feat)[(long)s_src[e] * 32 + k4];
  }
  __syncthreads();

  int og = t & 31, eg = t >> 5;
  float acc[8][4];
#pragma unroll
  for (int j = 0; j < 8; ++j)
#pragma unroll
    for (int d = 0; d < 4; ++d) acc[j][d] = 0.f;

  for (int k4 = 0; k4 < 32; ++k4) {
    float4 a[8];
#pragma unroll
    for (int j = 0; j < 8; ++j) a[j] = A4[eg * 8 + j][k4];
#pragma unroll
    for (int d = 0; d < 4; ++d) {
      float4 w = Wr4[(k4 * 4 + d) * 32 + og];
#pragma unroll
      for (int j = 0; j < 8; ++j) {
        float av = ((const float*)&a[j])[d];
        acc[j][0] += av * w.x;
        acc[j][1] += av * w.y;
        acc[j][2] += av * w.z;
        acc[j][3] += av * w.w;
      }
    }
  }

#pragma unroll
  for (int j = 0; j < 8; ++j) {
    int e = eg * 8 + j;
    float nm = s_norm[e];
    float* orow = out + (long)s_dst[e] * OUT_FEAT + og * 4;
#pragma unroll
    for (int d = 0; d < 4; ++d) atomicAdd(orow + d, acc[j][d] * nm);
  }
}

// ---------------------------------------------------------------------------
// Kernel 4: out = relu(out)
// ---------------------------------------------------------------------------
__global__ __launch_bounds__(256) void relu_kernel(float* __restrict__ out) {
  int idx = blockIdx.x * 256 + threadIdx.x;   // N_NODES*128/4 = 3.2M float4
  float4 v = ((const float4*)out)[idx];
  v.x = fmaxf(v.x, 0.f);
  v.y = fmaxf(v.y, 0.f);
  v.z = fmaxf(v.z, 0.f);
  v.w = fmaxf(v.w, 0.f);
  ((float4*)out)[idx] = v;
}

extern "C" void kernel_launch(void* const* d_in, const int* in_sizes, int n_in,
                              void* d_out, int out_size, void* d_ws, size_t ws_size,
                              hipStream_t stream) {
  const float* feat    = (const float*)d_in[0];
  const float* weight  = (const float*)d_in[1];
  const float* w_comp  = (const float*)d_in[2];
  const float* h_bias  = (const float*)d_in[3];
  const float* loop_w  = (const float*)d_in[4];
  const float* norm    = (const float*)d_in[5];
  const int*   src     = (const int*)d_in[6];
  const int*   dst     = (const int*)d_in[7];
  // d_in[8]=etypes, d_in[9]=section: sections are uniform (16384/rel), derived
  // from blockIdx instead of being read.
  float* W   = (float*)d_ws;           // 64*128*128 f32 = 4 MB scratch
  float* out = (float*)d_out;

  hipLaunchKernelGGL(compose_w_kernel, dim3((NUM_RELS * IN_FEAT * OUT_FEAT) / 256),
                     dim3(256), 0, stream, weight, w_comp, W);
  hipLaunchKernelGGL(init_out_kernel, dim3((N_NODES + 63) / 64),
                     dim3(256), 0, stream, feat, loop_w, h_bias, out);
  hipLaunchKernelGGL(edge_msg_kernel, dim3(E_TOTAL / 64),
                     dim3(256), 0, stream, feat, W, norm, src, dst, out);
  hipLaunchKernelGGL(relu_kernel, dim3((N_NODES * OUT_FEAT / 4) / 256),
                     dim3(256), 0, stream, out);
}